// Round 6
// baseline (26.839 us; speedup 1.0000x reference)
//
#include <hip/hip_runtime.h>

#define NCLS 10
#define IGN 10
#define HW_ (512 * 512)          // 262144 = 2^18
#define BATCH 8
#define NPIX (BATCH * HW_)       // 2097152
#define THREADS 256
#define PPT 2                    // px per thread per chunk
#define CHUNK_PX (THREADS * PPT) // 512
#define CHUNKS 4
#define BLOCK_PX (CHUNK_PX * CHUNKS)   // 2048
#define NBLOCKS (NPIX / BLOCK_PX)      // 1024
#define STAT_STRIDE 16
#define LAMBDA_UNC 0.5f
#define LOG2E 1.4426950408889634f
#define LN2 0.6931471805599453f

// Per-thread private LDS histogram region: 33 floats (30 stats + 3 dump
// slots for ignore pixels). Stride 33 ≡ 1 (mod 32) spreads banks.
#define RSTRIDE 33
#define HISTSZ (THREADS * RSTRIDE)   // 8448 floats = 33792 B

typedef const __attribute__((address_space(1))) void GV;
typedef __attribute__((address_space(3))) void LV;
__device__ __forceinline__ void gload_lds16(const void* g, void* l) {
    __builtin_amdgcn_global_load_lds((GV*)g, (LV*)l, 16, 0, 0);
}

__global__ void awce_zero_stats(float* __restrict__ stats) {
    int i = threadIdx.x;
    if (i < 30 * STAT_STRIDE) stats[i] = 0.0f;
}

template <bool ATOMIC>
__global__ __launch_bounds__(THREADS) void awce_main(
    const float* __restrict__ logits,
    const int* __restrict__ targets,
    float* __restrict__ outbuf)
{
    const int tid = threadIdx.x;
    const int wave = tid >> 6;
    const int lane = tid & 63;

    // stage[s][c][px]: c=0..9 logits channels, c=10 targets (as raw bits)
    __shared__ float stage[2][11][CHUNK_PX];   // 45056 B
    __shared__ float hist[HISTSZ];             // 33792 B
    __shared__ float red[4][32];               // 512 B

    const int g0 = blockIdx.x * BLOCK_PX;      // global pixel base of block
    const int b = g0 >> 18;                    // batch index (BLOCK_PX | HW_)
    const int hw0 = g0 & (HW_ - 1);
    const float* lbase = logits + (size_t)b * (NCLS * (size_t)HW_);

    // Stage chunk k into buffer s: 22 global_load_lds dwordx4, spread over waves.
    // Instr i: stream c=i>>1 (10 = targets), half h=i&1 (256 px per instr).
    auto stage_chunk = [&](int k, int s) {
#pragma unroll
        for (int i = wave; i < 22; i += 4) {
            const int c = i >> 1;
            const int h = i & 1;
            const int pxo = h * 256 + (lane << 2);     // 4 px per lane
            const void* gsrc;
            if (c < 10)
                gsrc = (const void*)(lbase + (size_t)c * HW_ + hw0 + k * CHUNK_PX + pxo);
            else
                gsrc = (const void*)(targets + g0 + k * CHUNK_PX + pxo);
            gload_lds16(gsrc, (void*)&stage[s][c][h * 256]);
        }
    };

    // Prologue: issue chunk 0 staging, zero hist under it, one barrier.
    stage_chunk(0, 0);
#pragma unroll
    for (int i = 0; i < RSTRIDE; ++i) hist[tid + i * THREADS] = 0.0f;
    __syncthreads();                    // drains stage(0) + hist visible

    float* hreg = &hist[tid * RSTRIDE];

#pragma unroll
    for (int k = 0; k < CHUNKS; ++k) {
        const int s = k & 1;
        // 1. ds_read chunk k into registers (data ready per previous barrier)
        float x[NCLS][PPT];
#pragma unroll
        for (int c = 0; c < NCLS; ++c) {
            float2 v = *reinterpret_cast<float2*>(&stage[s][c][tid * PPT]);
            x[c][0] = v.x; x[c][1] = v.y;
        }
        int2 tt = *reinterpret_cast<int2*>(&stage[s][10][tid * PPT]);
        int t2[PPT] = {tt.x, tt.y};
        __builtin_amdgcn_sched_barrier(0);   // pin reads before next staging
        // 2. issue chunk k+1 staging (flies under the math below)
        if (k + 1 < CHUNKS) stage_chunk(k + 1, s ^ 1);
        // 3. math + private-LDS hist scatter (hist no-alias stage -> no vm waits)
#pragma unroll
        for (int j = 0; j < PPT; ++j) {
            const int tj = t2[j];
            const int tc = (tj != IGN) ? tj : NCLS;   // NCLS -> dump slots 30..32
            float m = x[0][j];
#pragma unroll
            for (int c = 1; c < NCLS; ++c) m = fmaxf(m, x[c][j]);
            const float nm2 = -m * LOG2E;
            float sum = 0.f, dot = 0.f, xt = 0.f;
#pragma unroll
            for (int c = 0; c < NCLS; ++c) {
                const float xc = x[c][j];
                const float e = __builtin_amdgcn_exp2f(fmaf(xc, LOG2E, nm2));
                sum += e;
                dot = fmaf(e, xc, dot);
                xt = (tc == c) ? xc : xt;
            }
            const float lse = fmaf(__builtin_amdgcn_logf(sum), LN2, m);
            const float rs = __builtin_amdgcn_rcpf(sum);
            const float ent = fmaf(-dot, rs, lse);
            const float ce = lse - xt;
            float* p = hreg + 3 * tc;
            p[0] += 1.0f;
            p[1] += ent;
            p[2] += ce;
        }
        // 4. barrier: drains chunk k+1 staging; buf s free for k+2.
        __syncthreads();
    }

    // Stage 1: each wave reduces its 64 regions. Lane o<30: field f=o/10,
    // class c=o%10, region offset 3c+f (distinct 0..29 -> spread banks).
    if (lane < 30) {
        const int f = (lane >= 20) ? 2 : ((lane >= 10) ? 1 : 0);
        const int c = lane - f * 10;
        const int off = 3 * c + f;
        float v = 0.f;
#pragma unroll
        for (int r = 0; r < 64; ++r) v += hist[(wave * 64 + r) * RSTRIDE + off];
        red[wave][lane] = v;
    }
    __syncthreads();

    // Stage 2: combine 4 wave-partials; stat index = f*10+c = lane id.
    if (tid < 30) {
        float v = red[0][tid] + red[1][tid] + red[2][tid] + red[3][tid];
        if (ATOMIC) {
            atomicAdd(&outbuf[tid * STAT_STRIDE], v);
        } else {
            outbuf[tid * NBLOCKS + blockIdx.x] = v;
        }
    }
}

// Reduce 30 x NBLOCKS partials, compute final loss. One block, 512 threads.
__global__ __launch_bounds__(512) void awce_final_partials(
    const float* __restrict__ partials, float* __restrict__ out)
{
    __shared__ float sred[32];
    const int wave = threadIdx.x >> 6;
    const int lane = threadIdx.x & 63;
#pragma unroll
    for (int k = 0; k < 4; ++k) {
        const int c = wave + k * 8;
        if (c < 30) {
            const float* col = partials + (size_t)c * NBLOCKS;
            float s = 0.f;
#pragma unroll
            for (int i = 0; i < NBLOCKS / 64; ++i) s += col[lane + 64 * i];
#pragma unroll
            for (int o = 32; o >= 1; o >>= 1) s += __shfl_xor(s, o);
            if (lane == 0) sred[c] = s;
        }
    }
    __syncthreads();
    if (threadIdx.x == 0) {
        float cnt[NCLS], es[NCLS], cs[NCLS];
        float nv = 0.f;
#pragma unroll
        for (int c = 0; c < NCLS; ++c) {
            cnt[c] = sred[c];
            es[c]  = sred[10 + c];
            cs[c]  = sred[20 + c];
            nv += cnt[c];
        }
        float loss = 0.f;
#pragma unroll
        for (int c = 0; c < NCLS; ++c) {
            float wb = 0.f;
            if (cnt[c] > 0.f && nv > 0.f) wb = (nv - cnt[c]) / fmaxf(nv, 1.f);
            const float em = (cnt[c] > 0.f) ? es[c] / fmaxf(cnt[c], 1.f) : 0.f;
            const float wc = wb * (1.f + LAMBDA_UNC * em);
            loss = fmaf(cs[c], wc, loss);
        }
        out[0] = loss / (nv + 1e-6f);
    }
}

__global__ void awce_final_atomic(const float* __restrict__ stats, float* __restrict__ out) {
    if (threadIdx.x == 0) {
        float cnt[NCLS], es[NCLS], cs[NCLS];
        float nv = 0.f;
#pragma unroll
        for (int c = 0; c < NCLS; ++c) {
            cnt[c] = stats[c * STAT_STRIDE];
            es[c]  = stats[(10 + c) * STAT_STRIDE];
            cs[c]  = stats[(20 + c) * STAT_STRIDE];
            nv += cnt[c];
        }
        float loss = 0.f;
#pragma unroll
        for (int c = 0; c < NCLS; ++c) {
            float wb = 0.f;
            if (cnt[c] > 0.f && nv > 0.f) wb = (nv - cnt[c]) / fmaxf(nv, 1.f);
            const float em = (cnt[c] > 0.f) ? es[c] / fmaxf(cnt[c], 1.f) : 0.f;
            const float wc = wb * (1.f + LAMBDA_UNC * em);
            loss = fmaf(cs[c], wc, loss);
        }
        out[0] = loss / (nv + 1e-6f);
    }
}

extern "C" void kernel_launch(void* const* d_in, const int* in_sizes, int n_in,
                              void* d_out, int out_size, void* d_ws, size_t ws_size,
                              hipStream_t stream) {
    const float* logits = (const float*)d_in[0];
    const int* targets = (const int*)d_in[1];
    float* out = (float*)d_out;
    float* ws = (float*)d_ws;

    const size_t need = (size_t)30 * NBLOCKS * sizeof(float);   // 122,880 B
    if (ws_size >= need) {
        awce_main<false><<<NBLOCKS, THREADS, 0, stream>>>(logits, targets, ws);
        awce_final_partials<<<1, 512, 0, stream>>>(ws, out);
    } else {
        awce_zero_stats<<<1, 512, 0, stream>>>(ws);
        awce_main<true><<<NBLOCKS, THREADS, 0, stream>>>(logits, targets, ws);
        awce_final_atomic<<<1, 64, 0, stream>>>(ws, out);
    }
}